// Round 7
// baseline (116.289 us; speedup 1.0000x reference)
//
#include <hip/hip_runtime.h>
#include <hip/hip_bf16.h>
#include <stdint.h>

// Problem constants (fixed by reference)
#define NB    8
#define NS    2048
#define NE    1024
#define NH    16
#define NDK   64
#define MTOK  (NB*NS)      // 16384 tokens

typedef __attribute__((ext_vector_type(8))) short bf16x8;
typedef __attribute__((ext_vector_type(4))) float f32x4;

// round-to-nearest-even f32 -> bf16 bits
__device__ __forceinline__ ushort f2bf(float f) {
  uint32_t u = __float_as_uint(f);
  u += 0x7FFFu + ((u >> 16) & 1u);
  return (ushort)(u >> 16);
}

__device__ __forceinline__ void gload16(const void* g, void* l) {
  __builtin_amdgcn_global_load_lds(
      (const __attribute__((address_space(1))) void*)g,
      (__attribute__((address_space(3))) void*)l, 16, 0, 0);
}

// ---------------- f32 -> bf16 cast (vectorized) ----------------
__global__ __launch_bounds__(256) void cvt_bf16(const float* __restrict__ in,
                                                ushort* __restrict__ out, int n4) {
  int stride = gridDim.x * blockDim.x;
  for (int j = blockIdx.x * blockDim.x + threadIdx.x; j < n4; j += stride) {
    float4 v = ((const float4*)in)[j];
    ushort4 o;
    o.x = f2bf(v.x); o.y = f2bf(v.y); o.z = f2bf(v.z); o.w = f2bf(v.w);
    ((ushort4*)out)[j] = o;
  }
}

// ---------------- 256x256 8-phase bf16 GEMM (C = A * B^T) ----------------
// 512 threads = 8 waves (2 Mrows x 4 Ncols); BK=64; 16 K-tiles at K=1024.
// LDS 128 KB double-buffered; 128 B rows, 8 chunks of 16 B, XOR swizzle
// slot = chunk ^ (row&7); inverse pre-applied on the per-lane GLOBAL source
// (LDS dest of global_load_lds stays linear), XOR applied on ds_read.
// Phase q (4 per K-tile): kk = q>>1, mi-quad = q&1; 16 MFMA per phase.
// Staging: ALL four half-tiles of t+1 issue at q0(t) (buf^1 is dead from
// q3(t-1)-end). Counted waits (per-wave issue order B0,B1,A0,A1):
//   q0-end: vmcnt(8)  -> drains A-Mh1(t)      [issued 4 phases earlier]
//   q3-end: vmcnt(2)  -> drains B0,B1,A0(t+1) [issued 3 phases earlier]
// Never drains to 0 in the main loop (T4); last tile uses vmcnt(0) at q0.
// Each phase: {ds_read + stage -> barrier -> lgkmcnt(0) -> prio1 MFMA prio0
// -> [vmcnt] -> barrier}  (template-exact two barriers per phase).
#define GM 256
#define GN 256
#define GK 64

template<int EPI>   // 0: f32 C out; 1: cos(theta)*cos(acc) -> bf16 out
__global__ __launch_bounds__(512, 2) void gemm256(const ushort* __restrict__ A,
                                                  const ushort* __restrict__ Bm,
                                                  float* __restrict__ Cf,
                                                  ushort* __restrict__ Cq,
                                                  const float* __restrict__ theta,
                                                  int M, int N, int K) {
  __shared__ ushort As[2][GM * GK];   // 32 KB per buffer
  __shared__ ushort Bs[2][GN * GK];

  const int tid  = threadIdx.x;
  const int wid  = tid >> 6;
  const int lane = tid & 63;
  const int wr   = wid >> 2;        // 0..1
  const int wc   = wid & 3;         // 0..3
  const int fr   = lane & 15;
  const int ks   = lane >> 4;       // 0..3

  // XCD-chunked bijective swizzle: 256 blocks, 32 per XCD (A-panel locality)
  int b  = blockIdx.x;
  int wg = ((b & 7) << 5) | (b >> 3);
  int br = wg >> 2, bc = wg & 3;

  const ushort* Abase = A  + (size_t)(br * GM) * K;
  const ushort* Bbase = Bm + (size_t)(bc * GN) * K;

  // stage constants: lane covers (row base + lane>>3, slot lane&7);
  // source chunk = slot ^ (row&7)  (row&7 == lane>>3 for our 8-row stripes)
  const int srow = lane >> 3;
  const int sch8 = ((lane & 7) ^ srow) * 8;   // ushort offset of src chunk

  // ds_read slot offsets (ushorts): chunk = kk*4 + ks, slot = chunk ^ (row&7),
  // and row&7 == fr&7 for all fragment rows.
  const int sA0 = ((0 + ks) ^ (fr & 7)) * 8;  // kk = 0
  const int sA1 = ((4 + ks) ^ (fr & 7)) * 8;  // kk = 1

  f32x4 zero = {0.f, 0.f, 0.f, 0.f};
  f32x4 acc[8][4];
#pragma unroll
  for (int mi = 0; mi < 8; ++mi)
#pragma unroll
    for (int ni = 0; ni < 4; ++ni) acc[mi][ni] = zero;

  auto stA = [&](int buf, int mh, int kt) {
#pragma unroll
    for (int j = 0; j < 2; ++j) {
      int rl = mh * 128 + j * 64 + wid * 8;       // wave-uniform LDS row base
      gload16(Abase + (size_t)(rl + srow) * K + kt * GK + sch8,
              &As[buf][rl * GK]);
    }
  };
  auto stB = [&](int buf, int mh, int kt) {
#pragma unroll
    for (int j = 0; j < 2; ++j) {
      int rl = mh * 128 + j * 64 + wid * 8;
      gload16(Bbase + (size_t)(rl + srow) * K + kt * GK + sch8,
              &Bs[buf][rl * GK]);
    }
  };

  // prologue: stage tile 0 into buf 0 (order B0,B1,A0,A1); partial drain:
  // q0 reads need B0,B1,A0; A1 is drained by q0-end vmcnt(8).
  stB(0, 0, 0); stB(0, 1, 0); stA(0, 0, 0); stA(0, 1, 0);
  asm volatile("s_waitcnt vmcnt(2)" ::: "memory");
  __builtin_amdgcn_s_barrier();

  const int NKT = K / GK;   // 16
  int cur = 0;
  for (int t = 0; t < NKT; ++t) {
    const ushort* Ac = As[cur];
    const ushort* Bc = Bs[cur];
    const int nb = cur ^ 1;
    const bool pf = (t + 1 < NKT);
    bf16x8 af[4], bv[4];

    // ---- phase q0: kk=0, mi 0-3 ---- stage ALL of tile t+1
#pragma unroll
    for (int mi = 0; mi < 4; ++mi)
      af[mi] = *(const bf16x8*)&Ac[(mi * 32 + wr * 16 + fr) * GK + sA0];
#pragma unroll
    for (int ni = 0; ni < 4; ++ni)
      bv[ni] = *(const bf16x8*)&Bc[(ni * 64 + wc * 16 + fr) * GK + sA0];
    if (pf) { stB(nb, 0, t + 1); stB(nb, 1, t + 1); stA(nb, 0, t + 1); stA(nb, 1, t + 1); }
    __builtin_amdgcn_s_barrier();
    asm volatile("s_waitcnt lgkmcnt(0)" ::: "memory");
    __builtin_amdgcn_sched_barrier(0);
    __builtin_amdgcn_s_setprio(1);
#pragma unroll
    for (int mi = 0; mi < 4; ++mi)
#pragma unroll
      for (int ni = 0; ni < 4; ++ni)
        acc[mi][ni] = __builtin_amdgcn_mfma_f32_16x16x32_bf16(af[mi], bv[ni], acc[mi][ni], 0, 0, 0);
    __builtin_amdgcn_s_setprio(0);
    if (pf) asm volatile("s_waitcnt vmcnt(8)" ::: "memory");   // A-Mh1(t) landed
    else    asm volatile("s_waitcnt vmcnt(0)" ::: "memory");
    __builtin_amdgcn_s_barrier();

    // ---- phase q1: kk=0, mi 4-7 ----
#pragma unroll
    for (int mi = 0; mi < 4; ++mi)
      af[mi] = *(const bf16x8*)&Ac[((mi + 4) * 32 + wr * 16 + fr) * GK + sA0];
    __builtin_amdgcn_s_barrier();
    asm volatile("s_waitcnt lgkmcnt(0)" ::: "memory");
    __builtin_amdgcn_sched_barrier(0);
    __builtin_amdgcn_s_setprio(1);
#pragma unroll
    for (int mi = 0; mi < 4; ++mi)
#pragma unroll
      for (int ni = 0; ni < 4; ++ni)
        acc[mi + 4][ni] = __builtin_amdgcn_mfma_f32_16x16x32_bf16(af[mi], bv[ni], acc[mi + 4][ni], 0, 0, 0);
    __builtin_amdgcn_s_setprio(0);
    __builtin_amdgcn_s_barrier();

    // ---- phase q2: kk=1, mi 0-3 ----
#pragma unroll
    for (int mi = 0; mi < 4; ++mi)
      af[mi] = *(const bf16x8*)&Ac[(mi * 32 + wr * 16 + fr) * GK + sA1];
#pragma unroll
    for (int ni = 0; ni < 4; ++ni)
      bv[ni] = *(const bf16x8*)&Bc[(ni * 64 + wc * 16 + fr) * GK + sA1];
    __builtin_amdgcn_s_barrier();
    asm volatile("s_waitcnt lgkmcnt(0)" ::: "memory");
    __builtin_amdgcn_sched_barrier(0);
    __builtin_amdgcn_s_setprio(1);
#pragma unroll
    for (int mi = 0; mi < 4; ++mi)
#pragma unroll
      for (int ni = 0; ni < 4; ++ni)
        acc[mi][ni] = __builtin_amdgcn_mfma_f32_16x16x32_bf16(af[mi], bv[ni], acc[mi][ni], 0, 0, 0);
    __builtin_amdgcn_s_setprio(0);
    __builtin_amdgcn_s_barrier();

    // ---- phase q3: kk=1, mi 4-7 ----
#pragma unroll
    for (int mi = 0; mi < 4; ++mi)
      af[mi] = *(const bf16x8*)&Ac[((mi + 4) * 32 + wr * 16 + fr) * GK + sA1];
    __builtin_amdgcn_s_barrier();
    asm volatile("s_waitcnt lgkmcnt(0)" ::: "memory");
    __builtin_amdgcn_sched_barrier(0);
    __builtin_amdgcn_s_setprio(1);
#pragma unroll
    for (int mi = 0; mi < 4; ++mi)
#pragma unroll
      for (int ni = 0; ni < 4; ++ni)
        acc[mi + 4][ni] = __builtin_amdgcn_mfma_f32_16x16x32_bf16(af[mi], bv[ni], acc[mi + 4][ni], 0, 0, 0);
    __builtin_amdgcn_s_setprio(0);
    if (pf) asm volatile("s_waitcnt vmcnt(2)" ::: "memory");   // B0,B1,A0(t+1) landed
    __builtin_amdgcn_s_barrier();

    cur ^= 1;
  }

  // ---- epilogue ----
  const int colL = wc * 16 + fr;          // col mod 64 == colL (< 64)
  float ct = 0.f;
  if (EPI == 1) ct = __cosf(theta[colL]);
#pragma unroll
  for (int mi = 0; mi < 8; ++mi) {
    int row0 = br * GM + mi * 32 + wr * 16 + ks * 4;
#pragma unroll
    for (int ni = 0; ni < 4; ++ni) {
      size_t cbase = (size_t)row0 * N + bc * GN + ni * 64 + colL;
#pragma unroll
      for (int i = 0; i < 4; ++i) {
        if (EPI == 1)
          Cq[cbase + (size_t)i * N] = f2bf(ct * __cosf(acc[mi][ni][i]));
        else
          Cf[cbase + (size_t)i * N] = acc[mi][ni][i];
      }
    }
  }
}

// ---------------- per-token head-vs-head attention via MFMA ----------------
// 1 wave = 1 token. Scores: S = H^T H via self-product MFMA; softmax per
// column; PV A-frag = shuffled P (K padded to 32), B-frag = LDS-transposed H.
__global__ __launch_bounds__(256) void attn_quantum(const ushort* __restrict__ qqb,
                                                    ushort* __restrict__ aout) {
  __shared__ ushort T[4][64 * 32];
  int tid = threadIdx.x;
  int wv  = tid >> 6, l = tid & 63;
  size_t tok = (size_t)blockIdx.x * 4 + wv;
  const ushort* src = qqb + tok * NE;
  ushort* Tw = T[wv];

  int h  = l & 15;   // head / fragment row-col index
  int kb = l >> 4;   // k-block 0..3

  bf16x8 f0 = *(const bf16x8*)(src + h * 64 + kb * 8);
  bf16x8 f1 = *(const bf16x8*)(src + h * 64 + kb * 8 + 32);

  // transpose into LDS (swizzled): T[d][h] = H[d][h]
#pragma unroll
  for (int jj = 0; jj < 8; ++jj) {
    int d0 = kb * 8 + jj;
    int d1 = d0 + 32;
    Tw[d0 * 32 + (((h >> 3) ^ ((d0 >> 3) & 3)) << 3) + (h & 7)] = (ushort)f0[jj];
    Tw[d1 * 32 + (((h >> 3) ^ ((d1 >> 3) & 3)) << 3) + (h & 7)] = (ushort)f1[jj];
  }

  // scores: S[i][j] = sum_d qq[i*64+d]*qq[j*64+d]; frag is both A and B
  f32x4 sa = {0.f, 0.f, 0.f, 0.f};
  sa = __builtin_amdgcn_mfma_f32_16x16x32_bf16(f0, f0, sa, 0, 0, 0);
  sa = __builtin_amdgcn_mfma_f32_16x16x32_bf16(f1, f1, sa, 0, 0, 0);

  float s[4];
#pragma unroll
  for (int i = 0; i < 4; ++i) s[i] = sa[i] * 0.125f;   // 1/sqrt(64)

  float mx = fmaxf(fmaxf(s[0], s[1]), fmaxf(s[2], s[3]));
  mx = fmaxf(mx, __shfl_xor(mx, 16));
  mx = fmaxf(mx, __shfl_xor(mx, 32));
  float e[4], sum = 0.f;
#pragma unroll
  for (int i = 0; i < 4; ++i) { e[i] = __expf(s[i] - mx); sum += e[i]; }
  sum += __shfl_xor(sum, 16);
  sum += __shfl_xor(sum, 32);
  float inv = 1.f / sum;
#pragma unroll
  for (int i = 0; i < 4; ++i) e[i] *= inv;   // P[g][h], normalized

  // regroup P into PV A-frag: lane (h,kb) needs P[kb*8+jj][h], jj=0..7
  int s1 = h + (kb & 1) * 32;
  float q1[4], q2[4];
#pragma unroll
  for (int i = 0; i < 4; ++i) {
    q1[i] = __shfl(e[i], s1);
    q2[i] = __shfl(e[i], s1 + 16);
  }
  bool live = (kb < 2);
  bf16x8 pa;
#pragma unroll
  for (int i = 0; i < 4; ++i) {
    pa[i]     = live ? (short)f2bf(q1[i]) : (short)0;
    pa[4 + i] = live ? (short)f2bf(q2[i]) : (short)0;
  }

  __syncthreads();  // LDS transpose visible

  f32x4 o[4];
#pragma unroll
  for (int c = 0; c < 4; ++c) {
    int r = c * 16 + h;
    int slot = (kb & 1) ^ ((r >> 3) & 3);
    bf16x8 bfrag = *(const bf16x8*)&Tw[r * 32 + slot * 8];
    f32x4 z = {0.f, 0.f, 0.f, 0.f};
    o[c] = __builtin_amdgcn_mfma_f32_16x16x32_bf16(pa, bfrag, z, 0, 0, 0);
  }

  ushort* dst = aout + tok * NE;
#pragma unroll
  for (int c = 0; c < 4; ++c)
#pragma unroll
    for (int i = 0; i < 4; ++i)
      dst[(kb * 4 + i) * NDK + c * 16 + h] = f2bf(o[c][i]);
}

// ---------------- launch ----------------
extern "C" void kernel_launch(void* const* d_in, const int* in_sizes, int n_in,
                              void* d_out, int out_size, void* d_ws, size_t ws_size,
                              hipStream_t stream) {
  const float* x     = (const float*)d_in[0];
  const float* W     = (const float*)d_in[1];
  const float* theta = (const float*)d_in[2];
  float* out = (float*)d_out;

  char* ws = (char*)d_ws;
  ushort* xb  = (ushort*)ws;                                   // 32 MB
  ushort* Wb  = (ushort*)(ws + (size_t)MTOK * NE * 2);         // 2 MB
  ushort* qqb = (ushort*)(ws + (size_t)MTOK * NE * 2 + (size_t)NE * NE * 2); // 32 MB
  ushort* aout = xb;  // reuse: xb dead after GEMM1

  cvt_bf16<<<1024, 256, 0, stream>>>(x, xb, MTOK * NE / 4);
  cvt_bf16<<<256, 256, 0, stream>>>(W, Wb, NE * NE / 4);

  int nwg = (MTOK / GM) * (NE / GN);  // 64 * 4 = 256 blocks, 1 per CU
  gemm256<1><<<nwg, 512, 0, stream>>>(xb, Wb, nullptr, qqb, theta, MTOK, NE, NE);

  attn_quantum<<<MTOK / 4, 256, 0, stream>>>(qqb, aout);

  gemm256<0><<<nwg, 512, 0, stream>>>(aout, Wb, out, nullptr, nullptr, MTOK, NE, NE);
}

// Round 8
// 106.768 us; speedup vs baseline: 1.0892x; 1.0892x over previous
//
#include <hip/hip_runtime.h>
#include <hip/hip_bf16.h>
#include <stdint.h>

// Problem constants (fixed by reference)
#define NB    8
#define NS    2048
#define NE    1024
#define NH    16
#define NDK   64
#define MTOK  (NB*NS)      // 16384 tokens

typedef __attribute__((ext_vector_type(8))) short bf16x8;
typedef __attribute__((ext_vector_type(4))) float f32x4;

// round-to-nearest-even f32 -> bf16 bits
__device__ __forceinline__ ushort f2bf(float f) {
  uint32_t u = __float_as_uint(f);
  u += 0x7FFFu + ((u >> 16) & 1u);
  return (ushort)(u >> 16);
}

__device__ __forceinline__ void gload16(const void* g, void* l) {
  __builtin_amdgcn_global_load_lds(
      (const __attribute__((address_space(1))) void*)g,
      (__attribute__((address_space(3))) void*)l, 16, 0, 0);
}

// ---------------- f32 -> bf16 cast (vectorized) ----------------
__global__ __launch_bounds__(256) void cvt_bf16(const float* __restrict__ in,
                                                ushort* __restrict__ out, int n4) {
  int stride = gridDim.x * blockDim.x;
  for (int j = blockIdx.x * blockDim.x + threadIdx.x; j < n4; j += stride) {
    float4 v = ((const float4*)in)[j];
    ushort4 o;
    o.x = f2bf(v.x); o.y = f2bf(v.y); o.z = f2bf(v.z); o.w = f2bf(v.w);
    ((ushort4*)out)[j] = o;
  }
}

// ---------------- 256x256 8-phase bf16 GEMM (C = A * B^T) ----------------
// 512 threads = 8 waves (2 Mrows x 4 Ncols); BK=64; 16 K-tiles at K=1024.
// LDS 128 KB double-buffered; 128 B rows, 8 chunks of 16 B, XOR swizzle
// slot = chunk ^ (row&7).
// MODE 0 (GEMM2): A bf16 via global_load_lds (inverse swizzle on global src,
//   linear LDS dest), round-6 schedule: stage all-at-q0, vmcnt(8)@q0-end,
//   vmcnt(2)@q3-end, one barrier per phase. f32 C out.
// MODE 1 (GEMM1): A is f32 (x itself) reg-staged: global f32 loads issued at
//   q0(t) for t+1; at q3(t): vmcnt(0) (3 phases old -> no stall), in-reg RNE
//   cvt to bf16, 4x ds_write_b128 at swizzled slots, lgkmcnt(0), barrier.
//   B bf16 via global_load_lds as MODE 0. Epilogue cos(theta)*cos(acc)->bf16.
#define GM 256
#define GN 256
#define GK 64

template<int MODE>
__global__ __launch_bounds__(512, 2) void gemm256(const ushort* __restrict__ Ab,
                                                  const float* __restrict__ Af,
                                                  const ushort* __restrict__ Bm,
                                                  float* __restrict__ Cf,
                                                  ushort* __restrict__ Cq,
                                                  const float* __restrict__ theta,
                                                  int M, int N, int K) {
  __shared__ ushort As[2][GM * GK];   // 32 KB per buffer
  __shared__ ushort Bs[2][GN * GK];

  const int tid  = threadIdx.x;
  const int wid  = tid >> 6;
  const int lane = tid & 63;
  const int wr   = wid >> 2;        // 0..1
  const int wc   = wid & 3;         // 0..3
  const int fr   = lane & 15;
  const int ks   = lane >> 4;       // 0..3

  // XCD-chunked bijective swizzle: 256 blocks, 32 per XCD (A-panel locality)
  int b  = blockIdx.x;
  int wg = ((b & 7) << 5) | (b >> 3);
  int br = wg >> 2, bc = wg & 3;

  const ushort* Bbase = Bm + (size_t)(bc * GN) * K;
  const ushort* Abase = (MODE == 0) ? (Ab + (size_t)(br * GM) * K) : nullptr;
  const float4* Af4   = (MODE == 1) ? ((const float4*)Af) : nullptr;

  // gload_lds stage constants: lane covers (rowbase + lane>>3, slot lane&7);
  // source chunk = slot ^ (row&7), row&7 == lane>>3 for 8-row stripes.
  const int srow = lane >> 3;
  const int sch8 = ((lane & 7) ^ srow) * 8;   // ushort offset of src chunk

  // ds_read slot offsets: chunk = kk*4 + ks, slot = chunk ^ (row&7), row&7==fr&7
  const int sA0 = ((0 + ks) ^ (fr & 7)) * 8;  // kk = 0
  const int sA1 = ((4 + ks) ^ (fr & 7)) * 8;  // kk = 1

  // reg-stage constants (MODE 1): thread handles rows wid*32 + j*8 + srow,
  // chunk cs = lane&7 (8 f32 = 32B source), write slot = cs ^ (row&7) = cs ^ srow
  const int cs    = lane & 7;
  const int wslot = (cs ^ srow) * 8;          // ushort offset in LDS row

  f32x4 zero = {0.f, 0.f, 0.f, 0.f};
  f32x4 acc[8][4];
#pragma unroll
  for (int mi = 0; mi < 8; ++mi)
#pragma unroll
    for (int ni = 0; ni < 4; ++ni) acc[mi][ni] = zero;

  auto stA = [&](int buf, int mh, int kt) {
#pragma unroll
    for (int j = 0; j < 2; ++j) {
      int rl = mh * 128 + j * 64 + wid * 8;       // wave-uniform LDS row base
      gload16(Abase + (size_t)(rl + srow) * K + kt * GK + sch8,
              &As[buf][rl * GK]);
    }
  };
  auto stB = [&](int buf, int mh, int kt) {
#pragma unroll
    for (int j = 0; j < 2; ++j) {
      int rl = mh * 128 + j * 64 + wid * 8;
      gload16(Bbase + (size_t)(rl + srow) * K + kt * GK + sch8,
              &Bs[buf][rl * GK]);
    }
  };

  float4 ar[8];
  auto loadA = [&](int kt) {        // MODE 1: 8x dwordx4 (32 floats) per thread
#pragma unroll
    for (int j = 0; j < 4; ++j) {
      int rl = wid * 32 + j * 8 + srow;
      size_t base = (size_t)(br * GM + rl) * (K / 4) + kt * 16 + cs * 2;
      ar[2 * j]     = Af4[base];
      ar[2 * j + 1] = Af4[base + 1];
    }
  };
  auto writeA = [&](int buf) {      // cvt + 4x ds_write_b128 (swizzled)
#pragma unroll
    for (int j = 0; j < 4; ++j) {
      int rl = wid * 32 + j * 8 + srow;
      bf16x8 v;
      v[0] = (short)f2bf(ar[2*j].x);   v[1] = (short)f2bf(ar[2*j].y);
      v[2] = (short)f2bf(ar[2*j].z);   v[3] = (short)f2bf(ar[2*j].w);
      v[4] = (short)f2bf(ar[2*j+1].x); v[5] = (short)f2bf(ar[2*j+1].y);
      v[6] = (short)f2bf(ar[2*j+1].z); v[7] = (short)f2bf(ar[2*j+1].w);
      *(bf16x8*)&As[buf][rl * GK + wslot] = v;
    }
  };

  // ---- prologue: tile 0 into buf 0 ----
  stB(0, 0, 0); stB(0, 1, 0);
  if (MODE == 0) {
    stA(0, 0, 0); stA(0, 1, 0);
    asm volatile("s_waitcnt vmcnt(2)" ::: "memory");  // B0,B1,A0 landed; A1 via q0-end
  } else {
    loadA(0);
    asm volatile("s_waitcnt vmcnt(0)" ::: "memory");
    writeA(0);
    asm volatile("s_waitcnt lgkmcnt(0)" ::: "memory");
  }
  __builtin_amdgcn_s_barrier();

  const int NKT = K / GK;   // 16
  int cur = 0;
  for (int t = 0; t < NKT; ++t) {
    const ushort* Ac = As[cur];
    const ushort* Bc = Bs[cur];
    const int nb = cur ^ 1;
    const bool pf = (t + 1 < NKT);
    bf16x8 af[4], bv[4];

    // ---- phase q0: kk=0, mi 0-3 ---- stage t+1 (B gload; A per MODE)
#pragma unroll
    for (int mi = 0; mi < 4; ++mi)
      af[mi] = *(const bf16x8*)&Ac[(mi * 32 + wr * 16 + fr) * GK + sA0];
#pragma unroll
    for (int ni = 0; ni < 4; ++ni)
      bv[ni] = *(const bf16x8*)&Bc[(ni * 64 + wc * 16 + fr) * GK + sA0];
    if (pf) {
      stB(nb, 0, t + 1); stB(nb, 1, t + 1);
      if (MODE == 0) { stA(nb, 0, t + 1); stA(nb, 1, t + 1); }
      else           loadA(t + 1);
    }
    __builtin_amdgcn_sched_barrier(0);
    __builtin_amdgcn_s_setprio(1);
#pragma unroll
    for (int mi = 0; mi < 4; ++mi)
#pragma unroll
      for (int ni = 0; ni < 4; ++ni)
        acc[mi][ni] = __builtin_amdgcn_mfma_f32_16x16x32_bf16(af[mi], bv[ni], acc[mi][ni], 0, 0, 0);
    __builtin_amdgcn_s_setprio(0);
    __builtin_amdgcn_sched_barrier(0);
    if (MODE == 0) {
      if (pf) asm volatile("s_waitcnt vmcnt(8)" ::: "memory");   // A-Mh1(t) landed
      else    asm volatile("s_waitcnt vmcnt(0)" ::: "memory");
    }
    __builtin_amdgcn_s_barrier();

    // ---- phase q1: kk=0, mi 4-7 ----
#pragma unroll
    for (int mi = 0; mi < 4; ++mi)
      af[mi] = *(const bf16x8*)&Ac[((mi + 4) * 32 + wr * 16 + fr) * GK + sA0];
    __builtin_amdgcn_sched_barrier(0);
    __builtin_amdgcn_s_setprio(1);
#pragma unroll
    for (int mi = 0; mi < 4; ++mi)
#pragma unroll
      for (int ni = 0; ni < 4; ++ni)
        acc[mi + 4][ni] = __builtin_amdgcn_mfma_f32_16x16x32_bf16(af[mi], bv[ni], acc[mi + 4][ni], 0, 0, 0);
    __builtin_amdgcn_s_setprio(0);
    __builtin_amdgcn_sched_barrier(0);
    __builtin_amdgcn_s_barrier();

    // ---- phase q2: kk=1, mi 0-3 ----
#pragma unroll
    for (int mi = 0; mi < 4; ++mi)
      af[mi] = *(const bf16x8*)&Ac[(mi * 32 + wr * 16 + fr) * GK + sA1];
#pragma unroll
    for (int ni = 0; ni < 4; ++ni)
      bv[ni] = *(const bf16x8*)&Bc[(ni * 64 + wc * 16 + fr) * GK + sA1];
    __builtin_amdgcn_sched_barrier(0);
    __builtin_amdgcn_s_setprio(1);
#pragma unroll
    for (int mi = 0; mi < 4; ++mi)
#pragma unroll
      for (int ni = 0; ni < 4; ++ni)
        acc[mi][ni] = __builtin_amdgcn_mfma_f32_16x16x32_bf16(af[mi], bv[ni], acc[mi][ni], 0, 0, 0);
    __builtin_amdgcn_s_setprio(0);
    __builtin_amdgcn_sched_barrier(0);
    __builtin_amdgcn_s_barrier();

    // ---- phase q3: kk=1, mi 4-7 ---- (MODE 1: land A(t+1) into LDS)
#pragma unroll
    for (int mi = 0; mi < 4; ++mi)
      af[mi] = *(const bf16x8*)&Ac[((mi + 4) * 32 + wr * 16 + fr) * GK + sA1];
    __builtin_amdgcn_sched_barrier(0);
    __builtin_amdgcn_s_setprio(1);
#pragma unroll
    for (int mi = 0; mi < 4; ++mi)
#pragma unroll
      for (int ni = 0; ni < 4; ++ni)
        acc[mi + 4][ni] = __builtin_amdgcn_mfma_f32_16x16x32_bf16(af[mi], bv[ni], acc[mi + 4][ni], 0, 0, 0);
    __builtin_amdgcn_s_setprio(0);
    __builtin_amdgcn_sched_barrier(0);
    if (MODE == 0) {
      if (pf) asm volatile("s_waitcnt vmcnt(2)" ::: "memory");   // B0,B1,A0(t+1) landed
    } else {
      if (pf) {
        asm volatile("s_waitcnt vmcnt(0)" ::: "memory");   // loads are 3 phases old
        writeA(nb);
        asm volatile("s_waitcnt lgkmcnt(0)" ::: "memory"); // drain ds_writes pre-barrier
      }
    }
    __builtin_amdgcn_s_barrier();

    cur ^= 1;
  }

  // ---- epilogue ----
  const int colL = wc * 16 + fr;          // col mod 64 == colL (< 64)
  float ct = 0.f;
  if (MODE == 1) ct = __cosf(theta[colL]);
#pragma unroll
  for (int mi = 0; mi < 8; ++mi) {
    int row0 = br * GM + mi * 32 + wr * 16 + ks * 4;
#pragma unroll
    for (int ni = 0; ni < 4; ++ni) {
      size_t cbase = (size_t)row0 * N + bc * GN + ni * 64 + colL;
#pragma unroll
      for (int i = 0; i < 4; ++i) {
        if (MODE == 1)
          Cq[cbase + (size_t)i * N] = f2bf(ct * __cosf(acc[mi][ni][i]));
        else
          Cf[cbase + (size_t)i * N] = acc[mi][ni][i];
      }
    }
  }
}

// ---------------- per-token head-vs-head attention via MFMA ----------------
// 1 wave = 1 token. Scores: S = H^T H via self-product MFMA; softmax per
// column; PV A-frag = shuffled P (K padded to 32), B-frag = LDS-transposed H.
__global__ __launch_bounds__(256) void attn_quantum(const ushort* __restrict__ qqb,
                                                    ushort* __restrict__ aout) {
  __shared__ ushort T[4][64 * 32];
  int tid = threadIdx.x;
  int wv  = tid >> 6, l = tid & 63;
  size_t tok = (size_t)blockIdx.x * 4 + wv;
  const ushort* src = qqb + tok * NE;
  ushort* Tw = T[wv];

  int h  = l & 15;   // head / fragment row-col index
  int kb = l >> 4;   // k-block 0..3

  bf16x8 f0 = *(const bf16x8*)(src + h * 64 + kb * 8);
  bf16x8 f1 = *(const bf16x8*)(src + h * 64 + kb * 8 + 32);

  // transpose into LDS (swizzled): T[d][h] = H[d][h]
#pragma unroll
  for (int jj = 0; jj < 8; ++jj) {
    int d0 = kb * 8 + jj;
    int d1 = d0 + 32;
    Tw[d0 * 32 + (((h >> 3) ^ ((d0 >> 3) & 3)) << 3) + (h & 7)] = (ushort)f0[jj];
    Tw[d1 * 32 + (((h >> 3) ^ ((d1 >> 3) & 3)) << 3) + (h & 7)] = (ushort)f1[jj];
  }

  // scores: S[i][j] = sum_d qq[i*64+d]*qq[j*64+d]; frag is both A and B
  f32x4 sa = {0.f, 0.f, 0.f, 0.f};
  sa = __builtin_amdgcn_mfma_f32_16x16x32_bf16(f0, f0, sa, 0, 0, 0);
  sa = __builtin_amdgcn_mfma_f32_16x16x32_bf16(f1, f1, sa, 0, 0, 0);

  float s[4];
#pragma unroll
  for (int i = 0; i < 4; ++i) s[i] = sa[i] * 0.125f;   // 1/sqrt(64)

  float mx = fmaxf(fmaxf(s[0], s[1]), fmaxf(s[2], s[3]));
  mx = fmaxf(mx, __shfl_xor(mx, 16));
  mx = fmaxf(mx, __shfl_xor(mx, 32));
  float e[4], sum = 0.f;
#pragma unroll
  for (int i = 0; i < 4; ++i) { e[i] = __expf(s[i] - mx); sum += e[i]; }
  sum += __shfl_xor(sum, 16);
  sum += __shfl_xor(sum, 32);
  float inv = 1.f / sum;
#pragma unroll
  for (int i = 0; i < 4; ++i) e[i] *= inv;   // P[g][h], normalized

  // regroup P into PV A-frag: lane (h,kb) needs P[kb*8+jj][h], jj=0..7
  int s1 = h + (kb & 1) * 32;
  float q1[4], q2[4];
#pragma unroll
  for (int i = 0; i < 4; ++i) {
    q1[i] = __shfl(e[i], s1);
    q2[i] = __shfl(e[i], s1 + 16);
  }
  bool live = (kb < 2);
  bf16x8 pa;
#pragma unroll
  for (int i = 0; i < 4; ++i) {
    pa[i]     = live ? (short)f2bf(q1[i]) : (short)0;
    pa[4 + i] = live ? (short)f2bf(q2[i]) : (short)0;
  }

  __syncthreads();  // LDS transpose visible

  f32x4 o[4];
#pragma unroll
  for (int c = 0; c < 4; ++c) {
    int r = c * 16 + h;
    int slot = (kb & 1) ^ ((r >> 3) & 3);
    bf16x8 bfrag = *(const bf16x8*)&Tw[r * 32 + slot * 8];
    f32x4 z = {0.f, 0.f, 0.f, 0.f};
    o[c] = __builtin_amdgcn_mfma_f32_16x16x32_bf16(pa, bfrag, z, 0, 0, 0);
  }

  ushort* dst = aout + tok * NE;
#pragma unroll
  for (int c = 0; c < 4; ++c)
#pragma unroll
    for (int i = 0; i < 4; ++i)
      dst[(kb * 4 + i) * NDK + c * 16 + h] = f2bf(o[c][i]);
}

// ---------------- launch ----------------
extern "C" void kernel_launch(void* const* d_in, const int* in_sizes, int n_in,
                              void* d_out, int out_size, void* d_ws, size_t ws_size,
                              hipStream_t stream) {
  const float* x     = (const float*)d_in[0];
  const float* W     = (const float*)d_in[1];
  const float* theta = (const float*)d_in[2];
  float* out = (float*)d_out;

  char* ws = (char*)d_ws;
  ushort* Wb   = (ushort*)ws;                                  // 2 MB
  ushort* qqb  = (ushort*)(ws + (size_t)NE * NE * 2);          // 32 MB
  ushort* aout = (ushort*)(ws + (size_t)NE * NE * 2 + (size_t)MTOK * NE * 2); // 32 MB

  cvt_bf16<<<256, 256, 0, stream>>>(W, Wb, NE * NE / 4);

  int nwg = (MTOK / GM) * (NE / GN);  // 64 * 4 = 256 blocks, 1 per CU
  // GEMM1: A = x (f32, reg-staged + fused cvt), epilogue quantum-cos -> bf16
  gemm256<1><<<nwg, 512, 0, stream>>>(nullptr, x, Wb, nullptr, qqb, theta, MTOK, NE, NE);

  attn_quantum<<<MTOK / 4, 256, 0, stream>>>(qqb, aout);

  // GEMM2: A = aout (bf16, gload_lds), f32 out
  gemm256<0><<<nwg, 512, 0, stream>>>(aout, nullptr, Wb, out, nullptr, nullptr, MTOK, NE, NE);
}